// Round 1
// baseline (126.176 us; speedup 1.0000x reference)
//
#include <hip/hip_runtime.h>

// ARIMA(P=16, D=1, Q=16), S0 = 1048577, S = 1048576 diffed samples.
// Output: mean(err^2), one float.
//
// Strategy: fold head into input -> pure order-16 LTI IIR with zero history.
// 6 levels of even-odd squaring (A(z)A(-z)) turn it into a stride-64
// recurrence; final kernel runs 1024 waves with 64-substep warmup (4096
// original samples of pole decay) and reduces sum(e^2) via atomics.

#define S_TOTAL 1048576

// ---------------------------------------------------------------------------
// K1: compute u^(0) (tilde-x), level coefficients, head, out init.
//   t >= 17: u[t] = y_t - sum_k w_ar[k] y_{t-16+k}
//   t = 1..16: u[t] = y_t + sum_{j=1}^{t-1} a_j y_{t-j},  a_j = w_ma[16-j]
//   u[0] = 0.  out[0] = y_0^2 / S.
//   coeff[l*17 + j], l=0..5: g_j = (-1)^j c^(l)_j ; l=6: c^(6)_j.
// ---------------------------------------------------------------------------
__global__ void k_setup(const float* __restrict__ series,
                        const float* __restrict__ w_ar,
                        const float* __restrict__ w_ma,
                        float* __restrict__ u,
                        float* __restrict__ coeff,
                        float* __restrict__ out)
{
    int t = blockIdx.x * blockDim.x + threadIdx.x;
    if (t >= 17 && t < S_TOTAL) {
        float acc = series[t + 1] - series[t];   // y_t
        #pragma unroll
        for (int k = 0; k < 16; ++k) {
            float yk = series[t - 16 + k + 1] - series[t - 16 + k];
            acc -= w_ar[k] * yk;
        }
        u[t] = acc;
    } else if (t == 0) {
        u[0] = 0.0f;
    }

    if (blockIdx.x == 0 && threadIdx.x < 64) {
        int m = threadIdx.x;

        // head inputs u[1..16]
        if (m >= 1 && m <= 16) {
            float hv = series[m + 1] - series[m];        // y_m
            for (int j = 1; j < m; ++j)
                hv += w_ma[16 - j] * (series[m - j + 1] - series[m - j]);
            u[m] = hv;
        }
        if (m == 0) {
            float y0 = series[1] - series[0];
            out[0] = y0 * y0 * (1.0f / (float)S_TOTAL);
        }

        // coefficient squaring chain, lane m holds c_m (double), wave-wide shfl
        double cc = 0.0;
        if (m == 0) cc = 1.0;
        else if (m <= 16) cc = (double)w_ma[16 - m];   // a_m

        for (int l = 0; l < 6; ++l) {
            if (m <= 16)
                coeff[l * 17 + m] = (float)((m & 1) ? -cc : cc);  // g_m
            double b = 0.0;
            for (int i = 0; i <= 16; ++i) {
                double cci = __shfl(cc, i, 64);
                int j = 2 * m - i;
                int jc = (j < 0 || j > 16) ? 0 : j;
                double ccj = __shfl(cc, jc, 64);
                if (j >= 0 && j <= 16)
                    b += ((j & 1) ? -cci : cci) * ccj;   // (-1)^j c_i c_j
            }
            cc = b;
        }
        if (m <= 16)
            coeff[6 * 17 + m] = (float)cc;   // c^(6), no sign flip
    }
}

// ---------------------------------------------------------------------------
// K2: one squaring level.  out[t] = sum_{j=0}^{16} g_j in[t - j*stride]
// (index < 0 -> 0; in[0] == 0 inductively so out[0] stays 0)
// ---------------------------------------------------------------------------
__global__ void k_level(const float* __restrict__ in,
                        float* __restrict__ out,
                        const float* __restrict__ g,   // 17 coeffs (uniform)
                        int stride)
{
    int t = blockIdx.x * blockDim.x + threadIdx.x;
    if (t >= S_TOTAL) return;
    float acc = 0.0f;
    #pragma unroll
    for (int j = 0; j <= 16; ++j) {
        int idx = t - j * stride;
        float v = (idx >= 0) ? in[idx] : 0.0f;
        acc = fmaf(g[j], v, acc);
    }
    out[t] = acc;
}

// ---------------------------------------------------------------------------
// K3: stride-64 order-16 IIR + SSQ reduction.
// 1024 waves; wave c covers t in [c*1024, (c+1)*1024); lane = residue mod 64.
// 64 warmup substeps (= 4096 original samples) from zero history; exact for
// waves near the sequence start (true history IS zero there).
// ---------------------------------------------------------------------------
__global__ void k_iir(const float* __restrict__ u6,
                      const float* __restrict__ coeff,
                      float* __restrict__ out)
{
    const float* c6 = coeff + 6 * 17;
    float cc[16];
    #pragma unroll
    for (int j = 0; j < 16; ++j) cc[j] = c6[j + 1];   // uniform -> s_load

    int gtid = blockIdx.x * blockDim.x + threadIdx.x;
    int wave = gtid >> 6;
    int lane = threadIdx.x & 63;
    int base = wave * 1024 + lane;

    float h[16];
    #pragma unroll
    for (int j = 0; j < 16; ++j) h[j] = 0.0f;
    float acc = 0.0f;

    #pragma unroll
    for (int i = -64; i < 16; ++i) {
        int t = base + (i << 6);
        float uv = (t >= 0) ? u6[t] : 0.0f;
        float e = uv;
        #pragma unroll
        for (int j = 0; j < 16; ++j) e = fmaf(-cc[j], h[j], e);
        #pragma unroll
        for (int j = 15; j >= 1; --j) h[j] = h[j - 1];
        h[0] = e;
        if (i >= 0) acc += e * e;
    }

    #pragma unroll
    for (int off = 32; off > 0; off >>= 1)
        acc += __shfl_down(acc, off, 64);
    if (lane == 0)
        atomicAdd(out, acc * (1.0f / (float)S_TOTAL));
}

extern "C" void kernel_launch(void* const* d_in, const int* in_sizes, int n_in,
                              void* d_out, int out_size, void* d_ws, size_t ws_size,
                              hipStream_t stream) {
    const float* series = (const float*)d_in[0];
    const float* w_ar   = (const float*)d_in[1];
    const float* w_ma   = (const float*)d_in[2];
    float* out = (float*)d_out;

    float* ua    = (float*)d_ws;
    float* ub    = ua + S_TOTAL;
    float* coeff = ub + S_TOTAL;   // 7*17 floats

    const int B = 256;
    const int G = S_TOTAL / B;     // 4096

    k_setup<<<G, B, 0, stream>>>(series, w_ar, w_ma, ua, coeff, out);
    k_level<<<G, B, 0, stream>>>(ua, ub, coeff + 0 * 17, 1);
    k_level<<<G, B, 0, stream>>>(ub, ua, coeff + 1 * 17, 2);
    k_level<<<G, B, 0, stream>>>(ua, ub, coeff + 2 * 17, 4);
    k_level<<<G, B, 0, stream>>>(ub, ua, coeff + 3 * 17, 8);
    k_level<<<G, B, 0, stream>>>(ua, ub, coeff + 4 * 17, 16);
    k_level<<<G, B, 0, stream>>>(ub, ua, coeff + 5 * 17, 32);
    k_iir<<<256, B, 0, stream>>>(ua, coeff, out);
}

// Round 2
// 107.739 us; speedup vs baseline: 1.1711x; 1.1711x over previous
//
#include <hip/hip_runtime.h>

// ARIMA(P=16, D=1, Q=16), S0 = 1048577, S = 1048576 diffed samples.
// Output: mean(err^2), one float.
//
// Fully fused: each block owns CHUNK=2048 outputs. In LDS (ping-pong, padded
// addressing): series tile -> diff -> AR FIR (u0, with head fold) -> 6
// even-odd squaring levels (stride 1..32) -> stride-64 order-16 IIR with
// 16-substep warmup -> sum(e^2) -> atomicAdd. k_init precomputes level
// coefficients (fp64 chain) and seeds out[0] = y0^2/S.

#define S_TOTAL 1048576
#define CHUNK   2048
#define NBLK    (S_TOTAL / CHUNK)        // 512
#define WU      1024                     // IIR warmup lookback (16 substeps)
#define HALO    1008                     // 16*(2^6-1) level lookback
#define TILE    (CHUNK + WU + HALO)      // 4080 (= 255 runs of 16)
#define ZPAD    512                      // zero guard (unpadded elems)
#define ZPADP   544                      // ZPAD + ZPAD/16
#define MAXIDX  (TILE + 17)              // 4097 (series tile size)
#define BUFELEM (ZPADP + MAXIDX + (MAXIDX >> 4) + 8)   // 4905 floats

// padded LDS address: +1 float every 16 -> strided patterns stay <=2-way
__device__ __forceinline__ int pa(int idx) { return ZPADP + idx + (idx >> 4); }

// ---------------------------------------------------------------------------
// k_init: coefficient squaring chain (fp64, one wave) + out seed.
// coeff layout (floats): [0..101] G[l][j] = (-1)^j c^(l)_j (l=0..5),
//                        [102..118] c^(6)_j, [119..135] G0 (AR taps).
// ---------------------------------------------------------------------------
__global__ void k_init(const float* __restrict__ series,
                       const float* __restrict__ w_ar,
                       const float* __restrict__ w_ma,
                       float* __restrict__ coeff,
                       float* __restrict__ out)
{
    int m = threadIdx.x;   // 0..63
    if (m == 0) {
        float y0 = series[1] - series[0];
        out[0] = y0 * y0 * (1.0f / (float)S_TOTAL);
        coeff[119] = 1.0f;
    }
    if (m >= 1 && m <= 16) coeff[119 + m] = -w_ar[16 - m];

    double cc = 0.0;
    if (m == 0) cc = 1.0;
    else if (m <= 16) cc = (double)w_ma[16 - m];   // a_m

    for (int l = 0; l < 6; ++l) {
        if (m <= 16) coeff[l * 17 + m] = (float)((m & 1) ? -cc : cc);
        double b = 0.0;
        for (int i = 0; i <= 16; ++i) {
            double cci = __shfl(cc, i, 64);
            int j = 2 * m - i;
            int jc = (j < 0 || j > 16) ? 0 : j;
            double ccj = __shfl(cc, jc, 64);
            if (j >= 0 && j <= 16)
                b += ((j & 1) ? -cci : cci) * ccj;   // (-1)^j c_i c_j
        }
        cc = b;
    }
    if (m <= 16) coeff[102 + m] = (float)cc;
}

// ---------------------------------------------------------------------------
// one squaring level in LDS: out[idx] = sum_j g[j] * in[idx - j*S]
// run layout: thread computes 16 outputs of one residue class with a
// 32-element register window -> 2 LDS reads + 1 write per output.
// ---------------------------------------------------------------------------
template <int S>
__device__ __forceinline__ void stage(const float* __restrict__ in,
                                      float* __restrict__ out,
                                      const float* __restrict__ gp,
                                      int tid)
{
    float c[17];
    #pragma unroll
    for (int j = 0; j < 17; ++j) c[j] = gp[j];
    __syncthreads();   // previous stage's writes visible

    constexpr int RPC   = (TILE + 16 * S - 1) / (16 * S);
    constexpr int NRUNS = S * RPC;                 // <= 256 for all S here
    for (int run = tid; run < NRUNS; run += 256) {
        int r  = run & (S - 1);
        int w  = run / S;
        int ob = r + S * (w << 4);     // output base (i=0)
        int ib = ob - 16 * S;          // window base (m=0)
        float x[32];
        #pragma unroll
        for (int m = 0; m < 32; ++m) x[m] = in[pa(ib + S * m)];
        #pragma unroll
        for (int i = 0; i < 16; ++i) {
            float acc = 0.0f;
            #pragma unroll
            for (int j = 0; j < 17; ++j)
                acc = fmaf(c[j], x[16 + i - j], acc);
            int idx = ob + S * i;
            if (idx < TILE) out[pa(idx)] = acc;
        }
    }
}

// ---------------------------------------------------------------------------
__global__ __launch_bounds__(256) void k_fused(const float* __restrict__ series,
                                               const float* __restrict__ w_ma,
                                               const float* __restrict__ coeff,
                                               float* __restrict__ out)
{
    __shared__ float bufA[BUFELEM];
    __shared__ float bufB[BUFELEM];

    const int tid = threadIdx.x;
    const int Gs  = blockIdx.x * CHUNK;
    const int L   = Gs - WU - HALO;    // global index of tile idx 0

    // zero guards
    for (int i = tid; i < ZPADP; i += 256) { bufA[i] = 0.0f; bufB[i] = 0.0f; }

    // series tile: bufA[pa(i)] = series[L-16+i], i in [0, TILE+17)
    for (int i = tid; i < TILE + 17; i += 256) {
        int g = L - 16 + i;
        bufA[pa(i)] = (g >= 0) ? series[g] : 0.0f;
    }
    __syncthreads();

    // diff: bufB[pa(i)] = y[L-16+i]
    for (int i = tid; i < TILE + 16; i += 256) {
        int g = L - 16 + i;
        bufB[pa(i)] = (g >= 0) ? (bufA[pa(i + 1)] - bufA[pa(i)]) : 0.0f;
    }
    __syncthreads();

    // u0 stage (AR FIR + head fold): y (bufB, +16 shift) -> bufA
    {
        float c[17];
        #pragma unroll
        for (int j = 0; j < 17; ++j) c[j] = coeff[119 + j];   // G0
        for (int run = tid; run < (TILE >> 4); run += 256) {  // 255 runs
            int o0 = run << 4;
            float x[32];
            #pragma unroll
            for (int m = 0; m < 32; ++m) x[m] = bufB[pa(o0 + m)];
            #pragma unroll
            for (int i = 0; i < 16; ++i) {
                int idx = o0 + i;
                int g   = L + idx;
                float acc;
                if (g <= 0) {
                    acc = 0.0f;
                } else if (g <= 16) {          // head: u = y_g + sum a_j y_{g-j}
                    acc = x[16 + i];
                    for (int j = 1; j < g; ++j)
                        acc += w_ma[16 - j] * x[16 + i - j];
                } else {
                    acc = 0.0f;
                    #pragma unroll
                    for (int j = 0; j < 17; ++j)
                        acc = fmaf(c[j], x[16 + i - j], acc);
                }
                bufA[pa(idx)] = acc;
            }
        }
    }

    // 6 squaring levels (barrier at entry of each)
    stage<1 >(bufA, bufB, coeff + 0 * 17, tid);
    stage<2 >(bufB, bufA, coeff + 1 * 17, tid);
    stage<4 >(bufA, bufB, coeff + 2 * 17, tid);
    stage<8 >(bufB, bufA, coeff + 3 * 17, tid);
    stage<16>(bufA, bufB, coeff + 4 * 17, tid);
    stage<32>(bufB, bufA, coeff + 5 * 17, tid);
    // u6 now in bufA
    __syncthreads();

    // stride-64 order-16 IIR, 4 waves x (16 warmup + 8 output) substeps
    {
        float cc[16];
        #pragma unroll
        for (int j = 0; j < 16; ++j) cc[j] = coeff[102 + 1 + j];  // c6[1..16]
        int w    = tid >> 6;
        int lane = tid & 63;
        int base = WU + HALO + (w << 9) + lane;   // tile idx at substep i=0

        float h[16];
        #pragma unroll
        for (int j = 0; j < 16; ++j) h[j] = 0.0f;
        float acc = 0.0f;

        #pragma unroll
        for (int i = -16; i < 8; ++i) {
            float e = bufA[pa(base + i * 64)];
            #pragma unroll
            for (int j = 0; j < 16; ++j) e = fmaf(-cc[j], h[j], e);
            #pragma unroll
            for (int j = 15; j >= 1; --j) h[j] = h[j - 1];
            h[0] = e;
            if (i >= 0) acc += e * e;
        }

        #pragma unroll
        for (int off = 32; off > 0; off >>= 1)
            acc += __shfl_down(acc, off, 64);
        if (lane == 0)
            atomicAdd(out, acc * (1.0f / (float)S_TOTAL));
    }
}

extern "C" void kernel_launch(void* const* d_in, const int* in_sizes, int n_in,
                              void* d_out, int out_size, void* d_ws, size_t ws_size,
                              hipStream_t stream) {
    const float* series = (const float*)d_in[0];
    const float* w_ar   = (const float*)d_in[1];
    const float* w_ma   = (const float*)d_in[2];
    float* out   = (float*)d_out;
    float* coeff = (float*)d_ws;   // 136 floats

    k_init <<<1, 64, 0, stream>>>(series, w_ar, w_ma, coeff, out);
    k_fused<<<NBLK, 256, 0, stream>>>(series, w_ma, coeff, out);
}

// Round 3
// 89.099 us; speedup vs baseline: 1.4161x; 1.2092x over previous
//
#include <hip/hip_runtime.h>

// ARIMA(P=16, D=1, Q=16), S0 = 1048577, S = 1048576 diffed samples.
// Output: mean(err^2), one float.
//
// Fully fused cascade: each block owns CHUNK=1024 outputs. LDS ping-pong:
// series tile -> (diff+AR u0, head-folded) -> 6 even-odd squaring levels
// (stride 1..32) -> stride-64 order-16 IIR (A6) with 4-substep warmup ->
// block-reduced sum(e^2) -> one atomicAdd. 1024 blocks => 4 blocks/CU.

#define S_TOTAL 1048576
#define CHUNK   1024
#define NBLK    (S_TOTAL / CHUNK)        // 1024
#define WU      256                      // IIR warmup lookback (4 substeps)
#define HALO    1008                     // 16*(2^6-1) level lookback
#define TILE    (CHUNK + WU + HALO)      // 2288  (<= 255 runs of 9)
#define SER_N   (TILE + 26)              // series tile elements
#define ZPADP   544                      // padded zero-guard (covers idx >= -512)
#define BUFELEM (ZPADP + SER_N + (SER_N >> 4) + 4)

// padded LDS address: +1 float every 16 -> strided patterns stay <=2-way
__device__ __forceinline__ int pa(int idx) { return ZPADP + idx + (idx >> 4); }

// ---------------------------------------------------------------------------
// k_init: coefficient squaring chain (fp64, one wave) + out seed.
// coeff layout (floats): [0..101] G[l][j] = (-1)^j c^(l)_j (l=0..5),
//                        [102..118] c^(6)_j, [119..135] G0 (AR taps).
// ---------------------------------------------------------------------------
__global__ void k_init(const float* __restrict__ series,
                       const float* __restrict__ w_ar,
                       const float* __restrict__ w_ma,
                       float* __restrict__ coeff,
                       float* __restrict__ out)
{
    int m = threadIdx.x;   // 0..63
    if (m == 0) {
        float y0 = series[1] - series[0];
        out[0] = y0 * y0 * (1.0f / (float)S_TOTAL);
        coeff[119] = 1.0f;
    }
    if (m >= 1 && m <= 16) coeff[119 + m] = -w_ar[16 - m];

    double cc = 0.0;
    if (m == 0) cc = 1.0;
    else if (m <= 16) cc = (double)w_ma[16 - m];   // a_m

    for (int l = 0; l < 6; ++l) {
        if (m <= 16) coeff[l * 17 + m] = (float)((m & 1) ? -cc : cc);
        double b = 0.0;
        for (int i = 0; i <= 16; ++i) {
            double cci = __shfl(cc, i, 64);
            int j = 2 * m - i;
            int jc = (j < 0 || j > 16) ? 0 : j;
            double ccj = __shfl(cc, jc, 64);
            if (j >= 0 && j <= 16)
                b += ((j & 1) ? -cci : cci) * ccj;   // (-1)^j c_i c_j
        }
        cc = b;
    }
    if (m <= 16) coeff[102 + m] = (float)cc;
}

// ---------------------------------------------------------------------------
// one squaring level in LDS: out[idx] = sum_j g[j] * in[idx - j*S]
// runs of 9 outputs per thread, 25-element register window.
// NRUNS is exactly 255 or 256 for TILE=2288 and all S in {1..32}.
// ---------------------------------------------------------------------------
template <int LOG_S>
__device__ __forceinline__ void stage(const float* __restrict__ in,
                                      float* __restrict__ out,
                                      const float* __restrict__ gp,
                                      int tid)
{
    constexpr int S     = 1 << LOG_S;
    constexpr int NRUNS = S * ((TILE + 9 * S - 1) / (9 * S));
    static_assert(NRUNS <= 256, "runs must fit one pass");
    float c[17];
    #pragma unroll
    for (int j = 0; j < 17; ++j) c[j] = gp[j];
    __syncthreads();   // previous stage's writes visible
    if (tid < NRUNS) {
        int r  = tid & (S - 1);
        int q  = tid >> LOG_S;
        int ob = r + S * 9 * q;        // output base (i=0)
        float x[25];                   // window: in[ob + S*(m-16)], m=0..24
        #pragma unroll
        for (int m = 0; m < 25; ++m) x[m] = in[pa(ob + S * (m - 16))];
        #pragma unroll
        for (int i = 0; i < 9; ++i) {
            int idx = ob + S * i;
            if (idx < TILE) {
                float acc = 0.0f;
                #pragma unroll
                for (int j = 0; j < 17; ++j)
                    acc = fmaf(c[j], x[16 + i - j], acc);
                out[pa(idx)] = acc;
            }
        }
    }
}

// ---------------------------------------------------------------------------
__global__ __launch_bounds__(256) void k_fused(const float* __restrict__ series,
                                               const float* __restrict__ w_ma,
                                               const float* __restrict__ coeff,
                                               float* __restrict__ out)
{
    __shared__ float bufA[BUFELEM];
    __shared__ float bufB[BUFELEM];

    const int tid = threadIdx.x;
    const int Gs  = blockIdx.x * CHUNK;
    const int L   = Gs - (WU + HALO);    // global index of tile idx 0

    // zero guards
    for (int i = tid; i < ZPADP; i += 256) { bufA[i] = 0.0f; bufB[i] = 0.0f; }

    // series tile: bufA[pa(i)] = series[L-16+i]
    for (int i = tid; i < SER_N; i += 256) {
        int g = L - 16 + i;
        bufA[pa(i)] = (g >= 0) ? series[g] : 0.0f;
    }
    __syncthreads();

    // u0 pass (diff + AR FIR + head fold): series (bufA) -> bufB
    {
        float c[17];
        #pragma unroll
        for (int j = 0; j < 17; ++j) c[j] = coeff[119 + j];   // G0
        if (tid < 255) {
            int o0 = tid * 9;
            float s[26], y[25];
            #pragma unroll
            for (int m = 0; m < 26; ++m) s[m] = bufA[pa(o0 + m)];
            #pragma unroll
            for (int m = 0; m < 25; ++m) y[m] = s[m + 1] - s[m];
            #pragma unroll
            for (int i = 0; i < 9; ++i) {
                int idx = o0 + i;
                if (idx < TILE) {
                    int t = L + idx;
                    float acc;
                    if (t <= 0) {
                        acc = 0.0f;
                    } else if (t <= 16) {      // head: u = y_t + sum a_j y_{t-j}
                        acc = y[16 + i];
                        for (int j = 1; j < t; ++j)
                            acc += w_ma[16 - j] * y[16 + i - j];
                    } else {
                        acc = 0.0f;
                        #pragma unroll
                        for (int j = 0; j < 17; ++j)
                            acc = fmaf(c[j], y[16 + i - j], acc);
                    }
                    bufB[pa(idx)] = acc;
                }
            }
        }
    }

    // 6 squaring levels (barrier at entry of each)
    stage<0>(bufB, bufA, coeff + 0 * 17, tid);
    stage<1>(bufA, bufB, coeff + 1 * 17, tid);
    stage<2>(bufB, bufA, coeff + 2 * 17, tid);
    stage<3>(bufA, bufB, coeff + 3 * 17, tid);
    stage<4>(bufB, bufA, coeff + 4 * 17, tid);
    stage<5>(bufA, bufB, coeff + 5 * 17, tid);
    // u6 now in bufB
    __syncthreads();

    // stride-64 order-16 IIR (A6), 4 waves x (4 warmup + 4 output) substeps
    {
        float cc[16];
        #pragma unroll
        for (int j = 0; j < 16; ++j) cc[j] = coeff[102 + 1 + j];  // c6[1..16]
        int w    = tid >> 6;
        int lane = tid & 63;
        int base = WU + HALO + (w << 8) + lane;   // tile idx at substep i=0

        float h[16];
        #pragma unroll
        for (int j = 0; j < 16; ++j) h[j] = 0.0f;
        float acc = 0.0f;

        #pragma unroll
        for (int i = -4; i < 4; ++i) {
            float e = bufB[pa(base + (i << 6))];
            #pragma unroll
            for (int j = 0; j < 16; ++j) e = fmaf(-cc[j], h[j], e);
            #pragma unroll
            for (int j = 15; j >= 1; --j) h[j] = h[j - 1];
            h[0] = e;
            if (i >= 0) acc += e * e;
        }

        #pragma unroll
        for (int off = 32; off > 0; off >>= 1)
            acc += __shfl_down(acc, off, 64);
        if (lane == 0) bufA[w] = acc;   // bufA free now
        __syncthreads();
        if (tid == 0)
            atomicAdd(out, (bufA[0] + bufA[1] + bufA[2] + bufA[3])
                               * (1.0f / (float)S_TOTAL));
    }
}

extern "C" void kernel_launch(void* const* d_in, const int* in_sizes, int n_in,
                              void* d_out, int out_size, void* d_ws, size_t ws_size,
                              hipStream_t stream) {
    const float* series = (const float*)d_in[0];
    const float* w_ar   = (const float*)d_in[1];
    const float* w_ma   = (const float*)d_in[2];
    float* out   = (float*)d_out;
    float* coeff = (float*)d_ws;   // 136 floats

    k_init <<<1, 64, 0, stream>>>(series, w_ar, w_ma, coeff, out);
    k_fused<<<NBLK, 256, 0, stream>>>(series, w_ma, coeff, out);
}